// Round 1
// baseline (41.719 us; speedup 1.0000x reference)
//
#include <hip/hip_runtime.h>
#include <math.h>

#define NCLS 1784
#define NF4 446          // 1784 / 4
#define NBATCH 16384
#define LOG2E 1.4426950408889634f

// One wave (64 lanes) per row; 4 rows per 256-thread block.
__global__ __launch_bounds__(256) void cevp_row_kernel(
        const float* __restrict__ logits,
        const int* __restrict__ targets,
        const float* __restrict__ P,
        float* __restrict__ ws) {
    const int wave = threadIdx.x >> 6;          // 0..3
    const int lane = threadIdx.x & 63;
    const int row  = blockIdx.x * 4 + wave;
    if (row >= NBATCH) return;

    const float4* __restrict__ rp =
        reinterpret_cast<const float4*>(logits + (size_t)row * NCLS);

    // Load the whole row into registers: 7 float4 per lane (446 f4 per row).
    float4 v[7];
    #pragma unroll
    for (int k = 0; k < 7; ++k) {
        const int idx = lane + 64 * k;
        if (idx < NF4) {
            v[k] = rp[idx];
        } else {
            v[k] = make_float4(-INFINITY, -INFINITY, -INFINITY, -INFINITY);
        }
    }

    // Per-lane max + first-occurrence argmax (columns visited in increasing order).
    float m = -INFINITY;
    int   mi = NCLS;
    #pragma unroll
    for (int k = 0; k < 7; ++k) {
        const int base = (lane + 64 * k) * 4;
        const float* f = reinterpret_cast<const float*>(&v[k]);
        #pragma unroll
        for (int j = 0; j < 4; ++j) {
            if (f[j] > m) { m = f[j]; mi = base + j; }
        }
    }

    // Wave-wide (64-lane) argmax reduce; tie -> lowest index.
    #pragma unroll
    for (int off = 32; off > 0; off >>= 1) {
        const float om = __shfl_xor(m, off, 64);
        const int   oi = __shfl_xor(mi, off, 64);
        if (om > m || (om == m && oi < mi)) { m = om; mi = oi; }
    }

    // Sum of exp(v - m); padding lanes hold -inf -> exp -> 0.
    float s = 0.0f;
    #pragma unroll
    for (int k = 0; k < 7; ++k) {
        const float* f = reinterpret_cast<const float*>(&v[k]);
        #pragma unroll
        for (int j = 0; j < 4; ++j) {
            s += exp2f((f[j] - m) * LOG2E);
        }
    }
    #pragma unroll
    for (int off = 32; off > 0; off >>= 1) {
        s += __shfl_xor(s, off, 64);
    }

    if (lane == 0) {
        const int tgt = targets[row];
        const float lt = logits[(size_t)row * NCLS + tgt];   // L1/L2 hit (row just read)
        const float ce = logf(s) + m - lt;                    // -log_softmax at target
        const float pen = P[(size_t)tgt * NCLS + mi];         // penalty[target, argmax]
        ws[row] = ce + pen;
    }
}

// Deterministic fixed-order reduction of the 16384 per-row values.
__global__ __launch_bounds__(256) void cevp_reduce_kernel(
        const float* __restrict__ ws, float* __restrict__ out) {
    __shared__ float sm[256];
    float s = 0.0f;
    for (int i = threadIdx.x; i < NBATCH; i += 256) s += ws[i];
    sm[threadIdx.x] = s;
    __syncthreads();
    #pragma unroll
    for (int off = 128; off > 0; off >>= 1) {
        if (threadIdx.x < off) sm[threadIdx.x] += sm[threadIdx.x + off];
        __syncthreads();
    }
    if (threadIdx.x == 0) out[0] = sm[0] / (float)NBATCH;
}

extern "C" void kernel_launch(void* const* d_in, const int* in_sizes, int n_in,
                              void* d_out, int out_size, void* d_ws, size_t ws_size,
                              hipStream_t stream) {
    const float* logits  = (const float*)d_in[0];
    const int*   targets = (const int*)d_in[1];
    const float* P       = (const float*)d_in[2];
    float* out = (float*)d_out;
    float* ws  = (float*)d_ws;   // needs 16384 * 4 = 64 KB

    cevp_row_kernel<<<NBATCH / 4, 256, 0, stream>>>(logits, targets, P, ws);
    cevp_reduce_kernel<<<1, 256, 0, stream>>>(ws, out);
}

// Round 2
// 26.521 us; speedup vs baseline: 1.5730x; 1.5730x over previous
//
#include <hip/hip_runtime.h>
#include <math.h>

#define NCLS 1784
#define NF4 446          // 1784 / 4
#define NBATCH 16384
#define NBLOCKS (NBATCH / 4)   // 4096
#define LOG2E 1.4426950408889634f

// One wave (64 lanes) per row; 4 rows per 256-thread block.
// Each block writes ONE partial sum (ce+penalty over its 4 rows) to ws.
__global__ __launch_bounds__(256) void cevp_row_kernel(
        const float* __restrict__ logits,
        const int* __restrict__ targets,
        const float* __restrict__ P,
        float* __restrict__ ws) {
    const int wave = threadIdx.x >> 6;          // 0..3
    const int lane = threadIdx.x & 63;
    const int row  = blockIdx.x * 4 + wave;

    const float4* __restrict__ rp =
        reinterpret_cast<const float4*>(logits + (size_t)row * NCLS);

    // Load the whole row into registers: 7 float4 per lane (446 f4 per row).
    float4 v[7];
    #pragma unroll
    for (int k = 0; k < 7; ++k) {
        const int idx = lane + 64 * k;
        if (idx < NF4) {
            v[k] = rp[idx];
        } else {
            v[k] = make_float4(-INFINITY, -INFINITY, -INFINITY, -INFINITY);
        }
    }

    // Per-lane max + first-occurrence argmax (columns visited in increasing order).
    float m = -INFINITY;
    int   mi = NCLS;
    #pragma unroll
    for (int k = 0; k < 7; ++k) {
        const int base = (lane + 64 * k) * 4;
        const float* f = reinterpret_cast<const float*>(&v[k]);
        #pragma unroll
        for (int j = 0; j < 4; ++j) {
            if (f[j] > m) { m = f[j]; mi = base + j; }
        }
    }

    // Wave-wide (64-lane) argmax reduce; tie -> lowest index.
    #pragma unroll
    for (int off = 32; off > 0; off >>= 1) {
        const float om = __shfl_xor(m, off, 64);
        const int   oi = __shfl_xor(mi, off, 64);
        if (om > m || (om == m && oi < mi)) { m = om; mi = oi; }
    }

    // Sum of exp(v - m); padding lanes hold -inf -> exp -> 0.
    float s = 0.0f;
    #pragma unroll
    for (int k = 0; k < 7; ++k) {
        const float* f = reinterpret_cast<const float*>(&v[k]);
        #pragma unroll
        for (int j = 0; j < 4; ++j) {
            s += exp2f((f[j] - m) * LOG2E);
        }
    }
    #pragma unroll
    for (int off = 32; off > 0; off >>= 1) {
        s += __shfl_xor(s, off, 64);
    }

    __shared__ float part[4];
    if (lane == 0) {
        const int tgt = targets[row];
        const float lt = logits[(size_t)row * NCLS + tgt];   // L1/L2 hit (row just read)
        const float ce = logf(s) + m - lt;                    // -log_softmax at target
        const float pen = P[(size_t)tgt * NCLS + mi];         // penalty[target, argmax]
        part[wave] = ce + pen;
    }
    __syncthreads();
    if (threadIdx.x == 0) {
        ws[blockIdx.x] = (part[0] + part[1]) + (part[2] + part[3]);
    }
}

// Deterministic reduction of 4096 block partials: one float4 per thread.
__global__ __launch_bounds__(1024) void cevp_reduce_kernel(
        const float* __restrict__ ws, float* __restrict__ out) {
    __shared__ float sm[16];
    const int tid = threadIdx.x;
    const float4 v = reinterpret_cast<const float4*>(ws)[tid];
    float s = (v.x + v.y) + (v.z + v.w);
    #pragma unroll
    for (int off = 32; off > 0; off >>= 1) {
        s += __shfl_xor(s, off, 64);
    }
    if ((tid & 63) == 0) sm[tid >> 6] = s;
    __syncthreads();
    if (tid < 16) {
        float t = sm[tid];
        #pragma unroll
        for (int off = 8; off > 0; off >>= 1) {
            t += __shfl_xor(t, off, 64);   // lanes 0..15 active; offsets stay in-range
        }
        if (tid == 0) out[0] = t / (float)NBATCH;
    }
}

extern "C" void kernel_launch(void* const* d_in, const int* in_sizes, int n_in,
                              void* d_out, int out_size, void* d_ws, size_t ws_size,
                              hipStream_t stream) {
    const float* logits  = (const float*)d_in[0];
    const int*   targets = (const int*)d_in[1];
    const float* P       = (const float*)d_in[2];
    float* out = (float*)d_out;
    float* ws  = (float*)d_ws;   // needs 4096 * 4 = 16 KB

    cevp_row_kernel<<<NBLOCKS, 256, 0, stream>>>(logits, targets, P, ws);
    cevp_reduce_kernel<<<1, 1024, 0, stream>>>(ws, out);
}